// Round 4
// baseline (163.495 us; speedup 1.0000x reference)
//
#include <hip/hip_runtime.h>
#include <math.h>

typedef float f32x4 __attribute__((ext_vector_type(4)));
typedef __bf16 bf16x8 __attribute__((ext_vector_type(8)));
typedef __bf16 bf16x4 __attribute__((ext_vector_type(4)));

// ---------------------------------------------------------------------------
// JAX threefry2x32 (exact port) + dropout mask replication.
// ---------------------------------------------------------------------------
#define PARTITIONABLE 1

__device__ __forceinline__ void threefry2x32(unsigned k0, unsigned k1,
                                             unsigned c0, unsigned c1,
                                             unsigned &o0, unsigned &o1) {
  unsigned ks2 = k0 ^ k1 ^ 0x1BD11BDAu;
  unsigned x0 = c0 + k0, x1 = c1 + k1;
#define ROTL(v, n) (((v) << (n)) | ((v) >> (32 - (n))))
#define R4(a, b, c, d)                                   \
  { x0 += x1; x1 = ROTL(x1, a); x1 ^= x0;                \
    x0 += x1; x1 = ROTL(x1, b); x1 ^= x0;                \
    x0 += x1; x1 = ROTL(x1, c); x1 ^= x0;                \
    x0 += x1; x1 = ROTL(x1, d); x1 ^= x0; }
  R4(13, 15, 26, 6);  x0 += k1;  x1 += ks2 + 1u;
  R4(17, 29, 16, 24); x0 += ks2; x1 += k0 + 2u;
  R4(13, 15, 26, 6);  x0 += k0;  x1 += k1 + 3u;
  R4(17, 29, 16, 24); x0 += k1;  x1 += ks2 + 4u;
  R4(13, 15, 26, 6);  x0 += ks2; x1 += k0 + 5u;
  o0 = x0; o1 = x1;
#undef R4
#undef ROTL
}

__device__ __forceinline__ float dropout_scale(int layer, unsigned i) {
#if PARTITIONABLE
  unsigned d0, d1, y0, y1;
  threefry2x32(0u, 7u, 0u, (unsigned)layer, d0, d1);
  threefry2x32(d0, d1, 0u, i, y0, y1);
  unsigned bits = y0 ^ y1;
#else
  unsigned a0, b0, a1, b1v, y0, y1;
  threefry2x32(0u, 7u, 0u, 2u, a0, b0);
  threefry2x32(0u, 7u, 1u, 3u, a1, b1v);
  unsigned k0 = (layer == 0) ? a0 : b0;
  unsigned k1 = (layer == 0) ? a1 : b1v;
  const unsigned half = 16384u;
  unsigned lane = (i < half) ? 0u : 1u;
  unsigned j = lane ? (i - half) : i;
  threefry2x32(k0, k1, j, j + half, y0, y1);
  unsigned bits = lane ? y1 : y0;
#endif
  return (bits & 0x80000000u) ? 0.0f : 2.0f;
}

__device__ __forceinline__ float sigmoidf(float x) {
  return 1.0f / (1.0f + expf(-x));
}

// ---------------------------------------------------------------------------
// 1) Prenet (blocks 0..127) + WkT transpose prep (blocks 128..191).
//    Prenet also zeroes rnn_in[:,256:768] so att_part can atomicAdd into it.
// ---------------------------------------------------------------------------
__global__ __launch_bounds__(256) void prenet_kernel(
    const float* __restrict__ mels, const float* __restrict__ W1,
    const float* __restrict__ b1, const float* __restrict__ W2,
    const float* __restrict__ b2, const float* __restrict__ Wq,
    const float* __restrict__ Wk, __bf16* __restrict__ WkT,
    float* __restrict__ rnn_in, float* __restrict__ q_out) {
  int blk = blockIdx.x;
  int j = threadIdx.x;
  if (blk >= 128) {  // WkT prep: Wk [512][128] f32 -> WkT [128][512] bf16
    int gid = (blk - 128) * 256 + j;  // 0..16383
    int a = gid & 127;
    int k4 = (gid >> 7) * 4;
    bf16x4 w;
    for (int i = 0; i < 4; ++i) w[i] = (__bf16)Wk[(size_t)(k4 + i) * 128 + a];
    *reinterpret_cast<bf16x4*>(&WkT[(size_t)a * 512 + k4]) = w;
    return;
  }
  int b = blk;
  __shared__ float mel_s[80];
  __shared__ float x1_s[256];
  __shared__ float x2_s[256];
  if (j < 80) mel_s[j] = mels[b * 80 + j];
  // zero the attention slice (att_part accumulates into it)
  rnn_in[(size_t)b * 768 + 256 + j] = 0.0f;
  rnn_in[(size_t)b * 768 + 512 + j] = 0.0f;
  __syncthreads();
  float s = b1[j];
  for (int m = 0; m < 80; ++m) s = fmaf(mel_s[m], W1[m * 256 + j], s);
  s = fmaxf(s, 0.0f) * dropout_scale(0, (unsigned)(b * 256 + j));
  x1_s[j] = s;
  __syncthreads();
  float s2 = b2[j];
  for (int m = 0; m < 256; ++m) s2 = fmaf(x1_s[m], W2[m * 256 + j], s2);
  s2 = fmaxf(s2, 0.0f) * dropout_scale(1, (unsigned)(b * 256 + j));
  x2_s[j] = s2;
  rnn_in[(size_t)b * 768 + j] = s2;
  __syncthreads();
  if (j < 128) {
    float sq = 0.0f;
    for (int m = 0; m < 256; ++m) sq = fmaf(x2_s[m], Wq[m * 128 + j], sq);
    q_out[b * 128 + j] = sq;
  }
}

// ---------------------------------------------------------------------------
// 2) score via MFMA, double-buffered staging (loads for k+1 in flight under
//    MFMA on k; LDS write late). Block: 128t x 128a, 4 waves 2x2.
// ---------------------------------------------------------------------------
__global__ __launch_bounds__(256) void score_mfma_kernel(
    const float* __restrict__ enc, const __bf16* __restrict__ WkT,
    const float* __restrict__ bk, const float* __restrict__ q,
    const float* __restrict__ va_g, const float* __restrict__ bscore,
    float* __restrict__ score) {
  int b = blockIdx.y;
  int t0 = blockIdx.x * 128;
  int tid = threadIdx.x;
  int lane = tid & 63, wid = tid >> 6;
  int wr = wid >> 1, wc = wid & 1;
  __shared__ __align__(16) __bf16 Eb[2][128 * 64];
  __shared__ __align__(16) __bf16 Wb[2][128 * 64];
  __shared__ float red[128][4];

  f32x4 acc[4][4];
#pragma unroll
  for (int i = 0; i < 4; ++i)
#pragma unroll
    for (int j = 0; j < 4; ++j) acc[i][j] = (f32x4){0.f, 0.f, 0.f, 0.f};

  float qv[4], vav[4];
#pragma unroll
  for (int j = 0; j < 4; ++j) {
    int a = wc * 64 + j * 16 + (lane & 15);
    qv[j] = q[b * 128 + a] + bk[a];
    vav[j] = va_g[a];
  }

  float4 ereg[8];
  uint4 wreg[4];
  int er = tid >> 4, ek4 = (tid & 15) * 4;
  int wrw = tid >> 3, wkc = (tid & 7) * 8;

  auto LOADS = [&](int k0) {
#pragma unroll
    for (int p = 0; p < 8; ++p)
      ereg[p] = *reinterpret_cast<const float4*>(
          &enc[((size_t)(b * 512 + t0 + er + p * 16)) * 512 + k0 + ek4]);
#pragma unroll
    for (int p = 0; p < 4; ++p)
      wreg[p] = *reinterpret_cast<const uint4*>(
          &WkT[(size_t)(wrw + p * 32) * 512 + k0 + wkc]);
  };
  auto STORE = [&](int s) {
#pragma unroll
    for (int p = 0; p < 8; ++p) {
      int row = er + p * 16;
      bf16x4 w;
      w[0] = (__bf16)ereg[p].x; w[1] = (__bf16)ereg[p].y;
      w[2] = (__bf16)ereg[p].z; w[3] = (__bf16)ereg[p].w;
      *reinterpret_cast<bf16x4*>(&Eb[s][row * 64 + (ek4 ^ ((row & 7) << 3))]) = w;
    }
#pragma unroll
    for (int p = 0; p < 4; ++p) {
      int a = wrw + p * 32;
      *reinterpret_cast<uint4*>(&Wb[s][a * 64 + (wkc ^ ((a & 7) << 3))]) = wreg[p];
    }
  };

  LOADS(0);
  STORE(0);
  for (int it = 0; it < 8; ++it) {
    if (it < 7) LOADS((it + 1) * 64);
    __syncthreads();
    int s = it & 1;
#pragma unroll
    for (int kk = 0; kk < 64; kk += 32) {
      bf16x8 af[4], bfr[4];
      int kl = kk + (lane >> 4) * 8;
#pragma unroll
      for (int i = 0; i < 4; ++i) {
        int t = wr * 64 + i * 16 + (lane & 15);
        af[i] = *reinterpret_cast<const bf16x8*>(
            &Eb[s][t * 64 + (kl ^ ((t & 7) << 3))]);
      }
#pragma unroll
      for (int j = 0; j < 4; ++j) {
        int a = wc * 64 + j * 16 + (lane & 15);
        bfr[j] = *reinterpret_cast<const bf16x8*>(
            &Wb[s][a * 64 + (kl ^ ((a & 7) << 3))]);
      }
#pragma unroll
      for (int i = 0; i < 4; ++i)
#pragma unroll
        for (int j = 0; j < 4; ++j)
          acc[i][j] = __builtin_amdgcn_mfma_f32_16x16x32_bf16(
              af[i], bfr[j], acc[i][j], 0, 0, 0);
    }
    if (it < 7) STORE((it + 1) & 1);
  }

#pragma unroll
  for (int i = 0; i < 4; ++i) {
#pragma unroll
    for (int r = 0; r < 4; ++r) {
      float s = 0.0f;
#pragma unroll
      for (int j = 0; j < 4; ++j) s += tanhf(qv[j] + acc[i][j][r]) * vav[j];
      s += __shfl_xor(s, 1, 64);
      s += __shfl_xor(s, 2, 64);
      s += __shfl_xor(s, 4, 64);
      s += __shfl_xor(s, 8, 64);
      if ((lane & 15) == 0)
        red[wr * 64 + i * 16 + (lane >> 4) * 4 + r][wc] = s;
    }
  }
  __syncthreads();
  if (tid < 128)
    score[b * 512 + t0 + tid] = red[tid][0] + red[tid][1] + bscore[0];
}

// ---------------------------------------------------------------------------
// 3) Monotonic-attention scan
// ---------------------------------------------------------------------------
__global__ __launch_bounds__(512) void scan_kernel(
    const float* __restrict__ score, const float* __restrict__ prev_align,
    float* __restrict__ align_out) {
  int b = blockIdx.x, t = threadIdx.x;
  __shared__ float s[512];
  float p = sigmoidf(score[b * 512 + t]);
  float omp = 1.0f - p;
  s[t] = omp;
  __syncthreads();
  for (int off = 1; off < 512; off <<= 1) {
    float v = (t >= off) ? s[t - off] : 1.0f;
    __syncthreads();
    if (t >= off) s[t] *= v;
    __syncthreads();
  }
  float cp_excl = (t == 0) ? 1.0f : s[t - 1];
  __syncthreads();
  float denom = fminf(fmaxf(cp_excl, 1e-10f), 1.0f);
  float r = prev_align[b * 512 + t] / denom;
  s[t] = r;
  __syncthreads();
  for (int off = 1; off < 512; off <<= 1) {
    float v = (t >= off) ? s[t - off] : 0.0f;
    __syncthreads();
    if (t >= off) s[t] += v;
    __syncthreads();
  }
  align_out[b * 512 + t] = p * cp_excl * s[t];
}

// ---------------------------------------------------------------------------
// 4) attentions: atomicAdd chunk partials directly into rnn_in[:,256:768].
//    Whole-chunk early exit when all 64 alignments are exactly zero
//    (cumprod underflow makes most chunks zero).
// ---------------------------------------------------------------------------
__global__ __launch_bounds__(256) void att_part_kernel(
    const float* __restrict__ align, const float* __restrict__ enc,
    float* __restrict__ rnn_in) {
  int tc = blockIdx.x;
  int vt = blockIdx.y;
  int b = blockIdx.z;
  int tid = threadIdx.x;
  int v = vt * 256 + tid;
  __shared__ float al[64];
  __shared__ int flag;
  if (tid == 0) flag = 0;
  __syncthreads();
  if (tid < 64) {
    float a = align[b * 512 + tc * 64 + tid];
    al[tid] = a;
    if (a != 0.0f) flag = 1;
  }
  __syncthreads();
  if (!flag) return;
  float acc = 0.0f;
  for (int tt = 0; tt < 64; ++tt) {
    float a = al[tt];
    if (a != 0.0f)
      acc = fmaf(a, enc[((size_t)(b * 512 + tc * 64 + tt)) * 512 + v], acc);
  }
  atomicAdd(&rnn_in[(size_t)b * 768 + 256 + v], acc);
}

// ---------------------------------------------------------------------------
// 5) LSTM z partials via MFMA, 64-wide col blocks, dbuf A-staging, W-loads
//    hoisted ahead of MFMAs. Grid (64, 4); zp: seg = zp>>1, K-half = zp&1.
// ---------------------------------------------------------------------------
__global__ __launch_bounds__(256) void zgemm_mfma_kernel(
    const float* __restrict__ A0, int K0, const float* __restrict__ W0,
    const float* __restrict__ A1, int K1, const float* __restrict__ W1,
    float* __restrict__ parts) {
  int cb = blockIdx.x;   // 0..63
  int zp = blockIdx.y;   // 0..3
  int seg = zp >> 1, kh = zp & 1;
  const float* A = seg ? A1 : A0;
  const float* W = seg ? W1 : W0;
  int K = seg ? K1 : K0;
  int kc = K >> 1;                 // 384 or 512
  int kbeg = kh * kc;
  int nchunks = kc >> 6;           // 6 or 8
  int tid = threadIdx.x;
  int lane = tid & 63, wid = tid >> 6;
  int wr = wid >> 1, wc = wid & 1;
  __shared__ __align__(16) __bf16 Ab[2][128 * 64];

  f32x4 acc[4][2];
#pragma unroll
  for (int i = 0; i < 4; ++i)
#pragma unroll
    for (int j = 0; j < 2; ++j) acc[i][j] = (f32x4){0.f, 0.f, 0.f, 0.f};

  int n_base = cb * 64 + wc * 32 + (lane & 15);
  int koct = (lane >> 4) * 8;
  float4 areg[8];
  int ar = tid >> 4, ak4 = (tid & 15) * 4;

  auto LOADS_A = [&](int k0) {
#pragma unroll
    for (int p = 0; p < 8; ++p)
      areg[p] = *reinterpret_cast<const float4*>(
          &A[(size_t)(ar + p * 16) * K + k0 + ak4]);
  };
  auto STORE_A = [&](int s) {
#pragma unroll
    for (int p = 0; p < 8; ++p) {
      int row = ar + p * 16;
      bf16x4 w;
      w[0] = (__bf16)areg[p].x; w[1] = (__bf16)areg[p].y;
      w[2] = (__bf16)areg[p].z; w[3] = (__bf16)areg[p].w;
      *reinterpret_cast<bf16x4*>(&Ab[s][row * 64 + (ak4 ^ ((row & 7) << 3))]) = w;
    }
  };

  LOADS_A(kbeg);
  STORE_A(0);
  for (int it = 0; it < nchunks; ++it) {
    int k0 = kbeg + it * 64;
    if (it + 1 < nchunks) LOADS_A(k0 + 64);
    __syncthreads();
    int s = it & 1;
    // W fragments for both kk halves, loaded before MFMAs
    bf16x8 w0[2], w1[2];
#pragma unroll
    for (int jf = 0; jf < 2; ++jf) {
      const float* wq0 = W + (size_t)(k0 + koct) * 4096 + n_base + jf * 16;
      const float* wq1 = W + (size_t)(k0 + 32 + koct) * 4096 + n_base + jf * 16;
      bf16x8 a, bb;
#pragma unroll
      for (int j = 0; j < 8; ++j) {
        a[j] = (__bf16)wq0[(size_t)j * 4096];
        bb[j] = (__bf16)wq1[(size_t)j * 4096];
      }
      w0[jf] = a; w1[jf] = bb;
    }
#pragma unroll
    for (int i = 0; i < 4; ++i) {
      int t = wr * 64 + i * 16 + (lane & 15);
      bf16x8 af = *reinterpret_cast<const bf16x8*>(
          &Ab[s][t * 64 + (koct ^ ((t & 7) << 3))]);
      acc[i][0] = __builtin_amdgcn_mfma_f32_16x16x32_bf16(af, w0[0], acc[i][0], 0, 0, 0);
      acc[i][1] = __builtin_amdgcn_mfma_f32_16x16x32_bf16(af, w0[1], acc[i][1], 0, 0, 0);
    }
#pragma unroll
    for (int i = 0; i < 4; ++i) {
      int t = wr * 64 + i * 16 + (lane & 15);
      bf16x8 af = *reinterpret_cast<const bf16x8*>(
          &Ab[s][t * 64 + ((32 + koct) ^ ((t & 7) << 3))]);
      acc[i][0] = __builtin_amdgcn_mfma_f32_16x16x32_bf16(af, w1[0], acc[i][0], 0, 0, 0);
      acc[i][1] = __builtin_amdgcn_mfma_f32_16x16x32_bf16(af, w1[1], acc[i][1], 0, 0, 0);
    }
    if (it + 1 < nchunks) STORE_A((it + 1) & 1);
  }

  float* outp = parts + (size_t)zp * (128 * 4096);
#pragma unroll
  for (int i = 0; i < 4; ++i) {
#pragma unroll
    for (int jf = 0; jf < 2; ++jf) {
#pragma unroll
      for (int r = 0; r < 4; ++r) {
        int row = wr * 64 + i * 16 + ((lane >> 4) << 2) + r;
        int col = cb * 64 + wc * 32 + jf * 16 + (lane & 15);
        outp[(size_t)row * 4096 + col] = acc[i][jf][r];
      }
    }
  }
}

// ---------------------------------------------------------------------------
// 6) LSTM gates: z = sum of 4 parts + bias
// ---------------------------------------------------------------------------
__global__ __launch_bounds__(256) void gate_kernel(
    const float* __restrict__ parts, const float* __restrict__ bias,
    const float* __restrict__ c_prev, float* __restrict__ h_out,
    float* __restrict__ c_out) {
  int idx = blockIdx.x * 256 + threadIdx.x;
  int b = idx >> 10, j = idx & 1023;
  float zv[4];
  for (int g = 0; g < 4; ++g) {
    size_t off = (size_t)b * 4096 + g * 1024 + j;
    float s = bias[g * 1024 + j];
    for (int p = 0; p < 4; ++p) s += parts[(size_t)p * (128 * 4096) + off];
    zv[g] = s;
  }
  float ig = sigmoidf(zv[0]);
  float fg = sigmoidf(zv[1]);
  float gg = tanhf(zv[2]);
  float og = sigmoidf(zv[3]);
  float cn = fg * c_prev[idx] + ig * gg;
  float hn = og * tanhf(cn);
  h_out[idx] = hn;
  c_out[idx] = cn;
}

// ---------------------------------------------------------------------------
// 7) Projection: reads h2n (d_out) and attention slice of rnn_in directly.
// ---------------------------------------------------------------------------
__global__ __launch_bounds__(256) void proj_kernel(
    const float* __restrict__ h2n, const float* __restrict__ rnn_in,
    const float* __restrict__ Wp, const float* __restrict__ bp,
    float* __restrict__ mel, float* __restrict__ stops) {
  int b = blockIdx.x;
  int tid = threadIdx.x;
  __shared__ float row[1536];
  for (int i = tid; i < 1536; i += 256)
    row[i] = (i < 1024) ? h2n[(size_t)b * 1024 + i]
                        : rnn_in[(size_t)b * 768 + 256 + (i - 1024)];
  __syncthreads();
  if (tid < 81) {
    float s = bp[tid];
    for (int m = 0; m < 1536; ++m) s = fmaf(row[m], Wp[m * 81 + tid], s);
    if (tid < 80) mel[b * 80 + tid] = s;
    else stops[b] = s;
  }
}

// ---------------------------------------------------------------------------
extern "C" void kernel_launch(void* const* d_in, const int* in_sizes, int n_in,
                              void* d_out, int out_size, void* d_ws,
                              size_t ws_size, hipStream_t stream) {
  const float* enc  = (const float*)d_in[0];
  const float* mels = (const float*)d_in[1];
  const float* prev = (const float*)d_in[2];
  const float* h1   = (const float*)d_in[3];
  const float* c1   = (const float*)d_in[4];
  const float* h2   = (const float*)d_in[5];
  const float* c2   = (const float*)d_in[6];
  const float* Wp1  = (const float*)d_in[7];
  const float* bp1  = (const float*)d_in[8];
  const float* Wp2  = (const float*)d_in[9];
  const float* bp2  = (const float*)d_in[10];
  const float* Wq   = (const float*)d_in[11];
  const float* Wk   = (const float*)d_in[12];
  const float* bk   = (const float*)d_in[13];
  const float* va   = (const float*)d_in[14];
  const float* bsc  = (const float*)d_in[15];
  const float* Wx1  = (const float*)d_in[16];
  const float* Wh1  = (const float*)d_in[17];
  const float* bl1  = (const float*)d_in[18];
  const float* Wx2  = (const float*)d_in[19];
  const float* Wh2  = (const float*)d_in[20];
  const float* bl2  = (const float*)d_in[21];
  const float* Wpj  = (const float*)d_in[22];
  const float* bpj  = (const float*)d_in[23];

  float* out = (float*)d_out;
  float* mel    = out;            // 128*80
  float* stops  = out + 10240;    // 128
  float* aligno = out + 10368;    // 128*512
  float* h1n    = out + 75904;    // 128*1024
  float* c1n    = out + 206976;
  float* h2n    = out + 338048;
  float* c2n    = out + 469120;

  float* ws = (float*)d_ws;
  float* q_ws   = ws;              // 16384
  float* sc_ws  = ws + 16384;      // 65536
  float* rnn_in = ws + 81920;      // 128*768 = 98304
  float* parts  = ws + 180224;     // 4 * 128*4096 = 2,097,152
  // WkT (bf16, 128KB) aliases head of `parts` — consumed by score before zgemm
  __bf16* WkT = (__bf16*)parts;

  hipLaunchKernelGGL(prenet_kernel, dim3(192), dim3(256), 0, stream,
                     mels, Wp1, bp1, Wp2, bp2, Wq, Wk, WkT, rnn_in, q_ws);
  hipLaunchKernelGGL(score_mfma_kernel, dim3(4, 128), dim3(256), 0, stream,
                     enc, WkT, bk, q_ws, va, bsc, sc_ws);
  hipLaunchKernelGGL(scan_kernel, dim3(128), dim3(512), 0, stream,
                     sc_ws, prev, aligno);
  hipLaunchKernelGGL(att_part_kernel, dim3(8, 2, 128), dim3(256), 0, stream,
                     aligno, enc, rnn_in);
  hipLaunchKernelGGL(zgemm_mfma_kernel, dim3(64, 4), dim3(256), 0, stream,
                     rnn_in, 768, Wx1, h1, 1024, Wh1, parts);
  hipLaunchKernelGGL(gate_kernel, dim3(512), dim3(256), 0, stream,
                     parts, bl1, c1, h1n, c1n);
  hipLaunchKernelGGL(zgemm_mfma_kernel, dim3(64, 4), dim3(256), 0, stream,
                     h1n, 1024, Wx2, h2, 1024, Wh2, parts);
  hipLaunchKernelGGL(gate_kernel, dim3(512), dim3(256), 0, stream,
                     parts, bl2, c2, h2n, c2n);
  hipLaunchKernelGGL(proj_kernel, dim3(128), dim3(256), 0, stream,
                     h2n, rnn_in, Wpj, bpj, mel, stops);
}